// Round 11
// baseline (659.099 us; speedup 1.0000x reference)
//
#include <hip/hip_runtime.h>
#include <math.h>

// ---------------------------------------------------------------------------
// LongRec.  B=256, S=200, D=U=128, NC=50000.
// alpha = softmax over singleton axis == 1.0 -> h_att = h_d; W_a is dead.
// Pipeline (5 kernels):
//   k0_prep : 12 blocks: 128x128 weights fp32 -> bf16 k-swizzled B-frags;
//             block 0 also zeroes RSUM.
//   k12 : MFMA precompute -> PRE bf16.  R13: SINGLE wave-local LDS buffer
//         time-shared by tg then fg (DS ops are in-order per wave -> WAR
//         safe, no barrier); LDS 34.8->17.4KB -> launch_bounds(256,6) = 6
//         blocks/CU (was 4; kernel is latency-bound, R1: occ 21%/VALU 20%).
//         PRE stores DPP-packed to dwords (96 instead of 192 stores).
//   k3  : blocks < B_: 200-step recurrence (R6/R7 structure, ~198us floor).
//         blocks >= B_: W_out -> bf16 WT[n][k] transpose in its shadow.
//   k4a : logits via bf16 MFMA -> bf16 logits + fused sum(exp) atomicAdd.
//   k4c : out = exp(l)/rsum.
// ---------------------------------------------------------------------------

#define B_  256
#define S_  200
#define U_  128
#define NC  50000
#define NTOK (B_ * S_)       // 51200

// ws layout (in floats).
#define PRE_OFF   0
#define PRE_FL    (NTOK * 768 / 2)            // bf16 PRE: 19,660,800 floats
#define LOG_OFF   PRE_FL                      // bf16 logits: B_*NC/2 = 6.4M floats
#define WSWZ_OFF  (LOG_OFF + (B_ * NC / 2))   // 12*16384 ushort = 98304 floats
#define WT_OFF    (WSWZ_OFF + 98304)          // bf16 W_out^T: NC*U_/2 = 3.2M floats
#define HF_OFF    (WT_OFF + (NC * U_ / 2))    // Hb: B_*U_ ushort
#define RMAX_OFF  (HF_OFF + (B_ * U_ / 2))    // (unused slot)
#define RSUM_OFF  (RMAX_OFF + B_)

// PRE per-token layout (ushort idx): [decay(0)|xr(128)|xz(256)|xh(384)|fdir(512)|psi(640)]

typedef float  float4v  __attribute__((ext_vector_type(4)));
typedef short  short8v  __attribute__((ext_vector_type(8)));

// fast transcendentals: v_exp_f32 (2^x) + v_rcp_f32, ~2-3 ULP, branchless.
__device__ __forceinline__ float fsig(float x) {      // 1/(1+e^-x)
    return __builtin_amdgcn_rcpf(1.f + __builtin_amdgcn_exp2f(-1.4426950408889634f * x));
}
__device__ __forceinline__ float ftanh(float x) {     // 1 - 2/(e^{2x}+1)
    return 1.f - 2.f * __builtin_amdgcn_rcpf(1.f + __builtin_amdgcn_exp2f(2.8853900817779268f * x));
}
__device__ __forceinline__ float fexp(float x) {      // e^x
    return __builtin_amdgcn_exp2f(1.4426950408889634f * x);
}
__device__ __forceinline__ unsigned short f2bf(float f) {   // RNE
    unsigned int u = __float_as_uint(f);
    u = (u + 0x7fffu + ((u >> 16) & 1u)) >> 16;
    return (unsigned short)u;
}
__device__ __forceinline__ unsigned int pack2bf(float a, float b) {
    return (unsigned int)f2bf(a) | ((unsigned int)f2bf(b) << 16);
}
__device__ __forceinline__ float bf2f(unsigned short u) {
    return __uint_as_float((unsigned int)u << 16);
}
// Barrier draining only LDS (lgkmcnt) — global prefetches stay in flight.
__device__ __forceinline__ void bar_lds() {
    asm volatile("s_waitcnt lgkmcnt(0)\n\ts_barrier" ::: "memory");
}
// VALU cross-lane via DPP: 0xB1 quad_perm xor1, 0x4E quad_perm xor2,
// 0x141 row_half_mirror (xor7 within 8), 0x140 row_mirror (xor15 within 16).
template<int CTRL>
__device__ __forceinline__ float dppadd(float x) {
    return x + __int_as_float(
        __builtin_amdgcn_mov_dpp(__float_as_int(x), CTRL, 0xF, 0xF, true));
}
__device__ __forceinline__ float dppxor1(float x) {   // value from lane^1
    return __int_as_float(
        __builtin_amdgcn_mov_dpp(__float_as_int(x), 0xB1, 0xF, 0xF, true));
}

// ---------------------------------------------------------------------------
// k0_prep: 12 blocks: [128][128] fp32 -> bf16 swizzled
//          dst[((k>>5)*128 + n)*32 + (k&31)].  Block 0 zeroes RSUM.
__global__ __launch_bounds__(256) void k0_prep(
    const float* s0, const float* s1, const float* s2, const float* s3,
    const float* s4, const float* s5, const float* s6, const float* s7,
    const float* s8, const float* s9, const float* s10, const float* s11,
    unsigned short* __restrict__ dst, float* __restrict__ RSUM)
{
    const int bid = blockIdx.x;
    if (bid == 0 && threadIdx.x < B_) RSUM[threadIdx.x] = 0.f;
    const float* srcs[12] = { s0,s1,s2,s3,s4,s5,s6,s7,s8,s9,s10,s11 };
    const float* S = srcs[bid];
    unsigned short* D = dst + (size_t)bid * 16384;
    for (int i = threadIdx.x; i < 16384; i += 256) {
        int k5 = i & 31, n = (i >> 5) & 127, kb = i >> 12;
        D[i] = f2bf(S[(size_t)(kb * 32 + k5) * 128 + n]);
    }
}

// ---------------------------------------------------------------------------
// MFMA helpers (16x16x32 bf16).  A-frag: lane holds A[m0+(lane&15)][kb*32+quad*8+j].
// B-frag (swizzled W): lane holds W[kb*32+quad*8+j][nt*16+(lane&15)].
// C/D: col = lane&15, row = quad*4 + reg.
__device__ __forceinline__ void gemm_k128(const unsigned short (*A)[136],
                                          int m0, int l16, int quad,
                                          const unsigned short* __restrict__ Wm,
                                          float4v acc[8]) {
#pragma unroll
    for (int kb = 0; kb < 4; ++kb) {
        short8v av = *(const short8v*)&A[m0 + l16][kb * 32 + quad * 8];
#pragma unroll
        for (int nt = 0; nt < 8; ++nt) {
            short8v bv = *(const short8v*)(Wm + (((kb * 128) + nt * 16 + l16) * 32 + quad * 8));
            acc[nt] = __builtin_amdgcn_mfma_f32_16x16x32_bf16(av, bv, acc[nt], 0, 0, 0);
        }
    }
}
// A-frags held in registers (gathered directly from the embedding tables).
__device__ __forceinline__ void gemm_reg(const short8v a[4], int l16, int quad,
                                         const unsigned short* __restrict__ Wm,
                                         float4v acc[8]) {
#pragma unroll
    for (int kb = 0; kb < 4; ++kb) {
#pragma unroll
        for (int nt = 0; nt < 8; ++nt) {
            short8v bv = *(const short8v*)(Wm + (((kb * 128) + nt * 16 + l16) * 32 + quad * 8));
            acc[nt] = __builtin_amdgcn_mfma_f32_16x16x32_bf16(a[kb], bv, acc[nt], 0, 0, 0);
        }
    }
}
__device__ __forceinline__ void zero8(float4v acc[8]) {
#pragma unroll
    for (int i = 0; i < 8; ++i) acc[i] = (float4v)0.0f;
}
// 8 contiguous f32 -> one bf16 A-frag word (16B)
__device__ __forceinline__ short8v cvt8(const float* __restrict__ p) {
    float4 v0 = *(const float4*)p;
    float4 v1 = *(const float4*)(p + 4);
    union { unsigned int u[4]; short8v s; } r;
    r.u[0] = pack2bf(v0.x, v0.y);
    r.u[1] = pack2bf(v0.z, v0.w);
    r.u[2] = pack2bf(v1.x, v1.y);
    r.u[3] = pack2bf(v1.z, v1.w);
    return r.s;
}

// ---------------------------------------------------------------------------
// k12: fused MFMA precompute.  grid = NTOK/64, block = 256 (4 waves),
// wave w owns tokens t0+16w .. t0+16w+15.  No barriers: LDS is WAVE-LOCAL
// (each wave reads/writes only its 16 rows) and DS ops are in-order per
// wave, so one buffer is time-shared by tg then fg (WAR-safe).
// PRE stores DPP-packed: even l16 lanes store (v, lane^1's v) as one dword.
__global__ __launch_bounds__(256, 6) void k12_precompute(
    const int* __restrict__ item, const int* __restrict__ tix, const int* __restrict__ frq,
    const float* __restrict__ Ei, const float* __restrict__ Et, const float* __restrict__ Ef,
    const float* __restrict__ b_r, const float* __restrict__ b_z, const float* __restrict__ b_h,
    const float* __restrict__ b_tg, const float* __restrict__ b_fg,
    const float* __restrict__ b_delta, const float* __restrict__ b_f_dir, const float* __restrict__ b_psi,
    const unsigned short* __restrict__ WZ,
    unsigned short* __restrict__ PRE)
{
    __shared__ unsigned short Abuf[64][136];   // tg, then fg (bf16, A-layout)

    const int t0   = blockIdx.x * 64;
    const int tid  = threadIdx.x;
    const int lane = tid & 63;
    const int wid  = tid >> 6;
    const int quad = lane >> 4;
    const int l16  = lane & 15;
    const int m0   = wid * 16;

    // --- gather embedding rows straight into register A-frags ---
    const int tok = t0 + m0 + l16;
    const int it  = item[tok], tt = tix[tok], ft = frq[tok];
    const float* pei = Ei + (size_t)it * U_ + quad * 8;
    const float* pet = Et + (size_t)tt * U_ + quad * 8;
    const float* pef = Ef + (size_t)ft * U_ + quad * 8;

    short8v axi[4], axt[4], axf[4];
#pragma unroll
    for (int kb = 0; kb < 4; ++kb) axi[kb] = cvt8(pei + kb * 32);
#pragma unroll
    for (int kb = 0; kb < 4; ++kb) axt[kb] = cvt8(pet + kb * 32);
#pragma unroll
    for (int kb = 0; kb < 4; ++kb) axf[kb] = cvt8(pef + kb * 32);

    const unsigned short* WM0  = WZ;                 // W_xtg
    const unsigned short* WM1  = WZ + 1  * 16384;    // W_tg
    const unsigned short* WM2  = WZ + 2  * 16384;    // W_xfg
    const unsigned short* WM3  = WZ + 3  * 16384;    // W_fg
    const unsigned short* WM4  = WZ + 4  * 16384;    // W_xr
    const unsigned short* WM5  = WZ + 5  * 16384;    // W_xz
    const unsigned short* WM6  = WZ + 6  * 16384;    // W_xh
    const unsigned short* WM7  = WZ + 7  * 16384;    // W_delta top (tg rows)
    const unsigned short* WM8  = WZ + 8  * 16384;    // W_delta bot (fg rows)
    const unsigned short* WM9  = WZ + 9  * 16384;    // W_f_dir
    const unsigned short* WM10 = WZ + 10 * 16384;    // W_psi

    float4v acc[8], accD[8];
    const int tokbase = t0 + m0 + quad * 4;

// packed PRE store for one field: even-l16 lanes write (v, v_from_lane^1).
#define STORE_PRE(OFF, EXPR) do {                                            \
    _Pragma("unroll")                                                        \
    for (int nt = 0; nt < 8; ++nt) {                                         \
        int n = nt * 16 + l16;                                               \
        float bb = bvec[nt];                                                 \
        _Pragma("unroll")                                                    \
        for (int r = 0; r < 4; ++r) {                                        \
            float yv = acc[nt][r] + bb;                                      \
            float v  = (EXPR);                                               \
            float vn = dppxor1(v);                                           \
            if ((l16 & 1) == 0)                                              \
                *(unsigned int*)&PRE[(size_t)(tokbase + r) * 768 + (OFF) + n]\
                    = pack2bf(v, vn);                                        \
        }                                                                    \
    }                                                                        \
} while (0)

    float bvec[8];

    // ---- tg = sigmoid(xi@W_xtg + xt@W_tg + b_tg) -> Abuf ----
    zero8(acc);
    gemm_reg(axi, l16, quad, WM0, acc);
    gemm_reg(axt, l16, quad, WM1, acc);
#pragma unroll
    for (int nt = 0; nt < 8; ++nt) {
        int n = nt * 16 + l16;
        float bb = b_tg[n];
#pragma unroll
        for (int r = 0; r < 4; ++r)
            Abuf[m0 + quad * 4 + r][n] = f2bf(fsig(acc[nt][r] + bb));
    }

    // ---- xr, xz (xi-only reg GEMMs — hide tg's LDS write->read latency) ----
#pragma unroll
    for (int nt = 0; nt < 8; ++nt) bvec[nt] = b_r[nt * 16 + l16];
    zero8(acc);
    gemm_reg(axi, l16, quad, WM4, acc);
    STORE_PRE(128, yv);
#pragma unroll
    for (int nt = 0; nt < 8; ++nt) bvec[nt] = b_z[nt * 16 + l16];
    zero8(acc);
    gemm_reg(axi, l16, quad, WM5, acc);
    STORE_PRE(256, yv);

    // ---- delta top half: accD = tg @ W_delta[0:128]  (reads Abuf=tg) ----
    zero8(accD);
    gemm_k128(Abuf, m0, l16, quad, WM7, accD);

    // ---- fg = sigmoid(xi@W_xfg + xf@W_fg + b_fg) -> Abuf (overwrites tg;
    //      DS in-order per wave => WAR-safe, no barrier) ----
    zero8(acc);
    gemm_reg(axi, l16, quad, WM2, acc);
    gemm_reg(axf, l16, quad, WM3, acc);
#pragma unroll
    for (int nt = 0; nt < 8; ++nt) {
        int n = nt * 16 + l16;
        float bb = b_fg[n];
#pragma unroll
        for (int r = 0; r < 4; ++r)
            Abuf[m0 + quad * 4 + r][n] = f2bf(fsig(acc[nt][r] + bb));
    }

    // ---- xh (fills the fg LDS write->read gap) ----
#pragma unroll
    for (int nt = 0; nt < 8; ++nt) bvec[nt] = b_h[nt * 16 + l16];
    zero8(acc);
    gemm_reg(axi, l16, quad, WM6, acc);
    STORE_PRE(384, yv);

    // ---- delta bottom + decay = sigmoid(-y) ----
    gemm_k128(Abuf, m0, l16, quad, WM8, accD);
#pragma unroll
    for (int i = 0; i < 8; ++i) acc[i] = accD[i];
#pragma unroll
    for (int nt = 0; nt < 8; ++nt) bvec[nt] = b_delta[nt * 16 + l16];
    STORE_PRE(0, fsig(-yv));

    // ---- fdir = fg@W_f_dir + b ----
#pragma unroll
    for (int nt = 0; nt < 8; ++nt) bvec[nt] = b_f_dir[nt * 16 + l16];
    zero8(acc);
    gemm_k128(Abuf, m0, l16, quad, WM9, acc);
    STORE_PRE(512, yv);

    // ---- psi = sigmoid(fg@W_psi + b) ----
#pragma unroll
    for (int nt = 0; nt < 8; ++nt) bvec[nt] = b_psi[nt * 16 + l16];
    zero8(acc);
    gemm_k128(Abuf, m0, l16, quad, WM10, acc);
    STORE_PRE(640, fsig(yv));
#undef STORE_PRE
}

// ---------------------------------------------------------------------------
// k3: blocks < B_: one workgroup per batch row; 512 threads = 8 waves
//     (R6/R7 structure, measured floor ~198us).
//     blocks >= B_: W_out -> WT bf16 transpose (co-resident filler work).
__global__ __launch_bounds__(512, 2) void k3_scan(
    const unsigned short* __restrict__ PRE,
    const float* __restrict__ W_hr, const float* __restrict__ W_hz, const float* __restrict__ W_hh,
    const float* __restrict__ W_out, unsigned short* __restrict__ WT,
    unsigned short* __restrict__ Hb)
{
    if (blockIdx.x >= B_) {
        // ---- WT transpose branch: 128 n-cols per block, 512 threads ----
        const int bid2 = blockIdx.x - B_;
        const int n  = bid2 * 128 + ((int)threadIdx.x >> 2);
        const int k0 = ((int)threadIdx.x & 3) * 32;
        if (n < NC) {
#pragma unroll 8
            for (int i = 0; i < 32; ++i)
                WT[(size_t)n * 128 + k0 + i] = f2bf(W_out[(size_t)(k0 + i) * NC + n]);
        }
        return;
    }

    const int b    = blockIdx.x;
    const int tid  = threadIdx.x;
    const int lane = tid & 63;
    const int wid  = tid >> 6;          // 0..7
    const int cp   = lane >> 2;         // 0..15 (col selector)
    const int kg   = lane & 3;          // 0..3  (k-group = quad lane)

    const int colA = ((wid & 3) << 5) + (cp << 1);   // P1: 2 cols (even)
    const int colB = (wid << 4) + cp;                // P2: 1 col

    // --- loop-invariant weights pinned in VGPRs ---
    const float* Wrz = (wid < 4) ? W_hr : W_hz;
    float wrz[64];   // [(q*4+j)*2+c] = Wrz[16q+4kg+j][colA+c]
#pragma unroll
    for (int q = 0; q < 8; ++q)
#pragma unroll
        for (int j = 0; j < 4; ++j) {
            float2 wv = *(const float2*)&Wrz[(size_t)(16 * q + 4 * kg + j) * U_ + colA];
            wrz[(q * 4 + j) * 2 + 0] = wv.x;
            wrz[(q * 4 + j) * 2 + 1] = wv.y;
        }
    float whh[32];   // [q*4+j] = W_hh[16q+4kg+j][colB]
#pragma unroll
    for (int q = 0; q < 8; ++q)
#pragma unroll
        for (int j = 0; j < 4; ++j)
            whh[q * 4 + j] = W_hh[(size_t)(16 * q + 4 * kg + j) * U_ + colB];
#pragma unroll
    for (int k = 0; k < 64; ++k) asm volatile("" : "+v"(wrz[k]));
#pragma unroll
    for (int k = 0; k < 32; ++k) asm volatile("" : "+v"(whh[k]));

    __shared__ __align__(16) float hd[U_];
    __shared__ __align__(16) float rh[U_];
    __shared__ __align__(16) float zb[U_];
    if (tid < U_) hd[tid] = 0.f;    // h0 = 0 -> h_d(step 0) = 0

    const unsigned short* pre = PRE + (size_t)b * S_ * 768;
    // rolling prefetch pointers (point at step s+1 inside the loop)
    const unsigned short* pA = pre + ((wid < 4) ? 128 : 256) + colA;  // xr|xz
    const unsigned short* pX = pre + 384 + colB;  // xh; fdir=+128; psi=+256
    const unsigned short* pD = pre + 768 + colB;  // decay[s+1]

    float c_p0, c_p1, c_xh, c_fd, c_ps, c_dk;
    {
        ushort2 t = *(const ushort2*)pA;
        c_p0 = bf2f(t.x); c_p1 = bf2f(t.y);
        c_xh = bf2f(pX[0]); c_fd = bf2f(pX[128]); c_ps = bf2f(pX[256]);
        c_dk = bf2f(pD[0]);
    }
    bar_lds();

    float hn = 0.f;
    for (int s = 0; s < S_; ++s) {
        // prefetch step s+1 constants (stay in vmcnt flight across barriers)
        pA += 768; pX += 768; pD += 768;
        ushort2 tn = *(const ushort2*)pA;
        unsigned short nx = pX[0], nf = pX[128], np = pX[256], nd = pD[0];

        // ---- P1: r/z matvec over hd, 4-way acc split + DPP quad reduce ----
        float2 hdA = *(const float2*)&hd[colA];   // for rh = sig(r)*hd
        float a0[4] = {0.f,0.f,0.f,0.f}, a1[4] = {0.f,0.f,0.f,0.f};
#pragma unroll
        for (int q = 0; q < 8; ++q) {
            float4 hv = *(const float4*)&hd[16 * q + 4 * kg];
            int m = q & 3;
            a0[m] = fmaf(hv.x, wrz[(q*4+0)*2+0], a0[m]); a1[m] = fmaf(hv.x, wrz[(q*4+0)*2+1], a1[m]);
            a0[m] = fmaf(hv.y, wrz[(q*4+1)*2+0], a0[m]); a1[m] = fmaf(hv.y, wrz[(q*4+1)*2+1], a1[m]);
            a0[m] = fmaf(hv.z, wrz[(q*4+2)*2+0], a0[m]); a1[m] = fmaf(hv.z, wrz[(q*4+2)*2+1], a1[m]);
            a0[m] = fmaf(hv.w, wrz[(q*4+3)*2+0], a0[m]); a1[m] = fmaf(hv.w, wrz[(q*4+3)*2+1], a1[m]);
        }
        float s0 = (a0[0] + a0[1]) + (a0[2] + a0[3]);
        float s1 = (a1[0] + a1[1]) + (a1[2] + a1[3]);
        s0 = dppadd<0xB1>(s0); s0 = dppadd<0x4E>(s0);
        s1 = dppadd<0xB1>(s1); s1 = dppadd<0x4E>(s1);
        if (kg == 0) {
            float g0 = fsig(c_p0 + s0), g1 = fsig(c_p1 + s1);
            if (wid < 4) *(float2*)&rh[colA] = make_float2(g0 * hdA.x, g1 * hdA.y);
            else         *(float2*)&zb[colA] = make_float2(g0, g1);
        }
        bar_lds();   // rh, zb ready

        // ---- P2: h matvec over rh (all 8 waves) + update ----
        float z_  = zb[colB];
        float hd_ = hd[colB];
        float c2[4] = {0.f,0.f,0.f,0.f};
#pragma unroll
        for (int q = 0; q < 8; ++q) {
            float4 rv = *(const float4*)&rh[16 * q + 4 * kg];
            int m = q & 3;
            c2[m] = fmaf(rv.x, whh[q * 4 + 0], c2[m]);
            c2[m] = fmaf(rv.y, whh[q * 4 + 1], c2[m]);
            c2[m] = fmaf(rv.z, whh[q * 4 + 2], c2[m]);
            c2[m] = fmaf(rv.w, whh[q * 4 + 3], c2[m]);
        }
        float s2 = (c2[0] + c2[1]) + (c2[2] + c2[3]);
        s2 = dppadd<0xB1>(s2); s2 = dppadd<0x4E>(s2);
        float hb = ftanh(c_xh + s2);
        float hf = ftanh(hb + c_fd);
        float hc = (1.f - c_ps) * hb + c_ps * hf;
        hn = (1.f - z_) * hd_ + z_ * hc;          // alpha==1 -> h_att = h_d
        if (kg == 0) hd[colB] = c_dk * hn;        // decay[s+1] * h_new
        bar_lds();   // hd ready for next step

        c_p0 = bf2f(tn.x); c_p1 = bf2f(tn.y);
        c_xh = bf2f(nx); c_fd = bf2f(nf); c_ps = bf2f(np); c_dk = bf2f(nd);
    }
    if (kg == 0) Hb[(size_t)b * U_ + colB] = f2bf(hn);
}

// ---------------------------------------------------------------------------
// k4a: logits = h @ W_out + b_out via bf16 MFMA -> bf16 logits, plus fused
// per-row sum(exp(logit)) into RSUM (DPP 16-lane row reduce + atomicAdd).
// Sums use the bf16-ROUNDED logits so they match exactly what k4c re-exps.
__global__ __launch_bounds__(256) void k4a_logits(
    const unsigned short* __restrict__ Hb, const unsigned short* __restrict__ WT,
    const float* __restrict__ b_out, unsigned short* __restrict__ LOGb,
    float* __restrict__ RSUM)
{
    const int tid  = threadIdx.x;
    const int lane = tid & 63, wid = tid >> 6;
    const int quad = lane >> 4, l16 = lane & 15;
    const int rb = blockIdx.y * 64 + wid * 16;
    const int cb = blockIdx.x * 128;

    short8v av[4];
#pragma unroll
    for (int kb = 0; kb < 4; ++kb)
        av[kb] = *(const short8v*)&Hb[(size_t)(rb + l16) * 128 + kb * 32 + quad * 8];

    float4v acc[8];
#pragma unroll
    for (int i = 0; i < 8; ++i) acc[i] = (float4v)0.0f;

#pragma unroll
    for (int kb = 0; kb < 4; ++kb) {
#pragma unroll
        for (int nt = 0; nt < 8; ++nt) {
            short8v bv = *(const short8v*)&WT[(size_t)(cb + nt * 16 + l16) * 128 + kb * 32 + quad * 8];
            acc[nt] = __builtin_amdgcn_mfma_f32_16x16x32_bf16(av[kb], bv, acc[nt], 0, 0, 0);
        }
    }
    float esum[4] = { 0.f, 0.f, 0.f, 0.f };
#pragma unroll
    for (int nt = 0; nt < 8; ++nt) {
        int n = cb + nt * 16 + l16;
        float bb = (n < NC) ? b_out[n] : 0.f;
#pragma unroll
        for (int r = 0; r < 4; ++r) {
            float v  = acc[nt][r] + bb;
            float vr = bf2f(f2bf(v));              // the value k4c will see
            float vn = dppxor1(v);                 // lane^1's value (col n^1)
            if (((l16 & 1) == 0) && n < NC) {      // NC even -> n+1 < NC too
                *(unsigned int*)((char*)LOGb +
                    ((size_t)(rb + quad * 4 + r) * NC + n) * 2) = pack2bf(v, vn);
            }
            if (n < NC) esum[r] += fexp(vr);
        }
    }
    // reduce esum over the 16-lane row (xor1, xor2, xor7, xor15) + atomic
#pragma unroll
    for (int r = 0; r < 4; ++r) {
        float sr = esum[r];
        sr = dppadd<0xB1>(sr);   // xor1
        sr = dppadd<0x4E>(sr);   // xor2
        sr = dppadd<0x141>(sr);  // row_half_mirror: combine 4-groups within 8
        sr = dppadd<0x140>(sr);  // row_mirror: combine 8-groups within 16
        if (l16 == 0) atomicAdd(&RSUM[rb + quad * 4 + r], sr);
    }
}

// ---------------------------------------------------------------------------
// k4c: out = exp(l)/rsum, 8 elements/thread (short8v in, 2x float4 out).
__global__ __launch_bounds__(256) void k4c_norm(
    const unsigned short* __restrict__ LOGb, const float* __restrict__ RSUM,
    float* __restrict__ out)
{
    const int r  = blockIdx.y;
    const int c8 = blockIdx.x * 256 + threadIdx.x;
    if (c8 < NC / 8) {
        short8v v = *(const short8v*)(LOGb + (size_t)r * NC + c8 * 8);
        float inv = __builtin_amdgcn_rcpf(RSUM[r]);
        float4 o0, o1;
        o0.x = fexp(bf2f((unsigned short)v[0])) * inv;
        o0.y = fexp(bf2f((unsigned short)v[1])) * inv;
        o0.z = fexp(bf2f((unsigned short)v[2])) * inv;
        o0.w = fexp(bf2f((unsigned short)v[3])) * inv;
        o1.x = fexp(bf2f((unsigned short)v[4])) * inv;
        o1.y = fexp(bf2f((unsigned short)v[5])) * inv;
        o1.z = fexp(bf2f((unsigned short)v[6])) * inv;
        o1.w = fexp(bf2f((unsigned short)v[7])) * inv;
        float* po = out + (size_t)r * NC + c8 * 8;
        *(float4*)po       = o0;
        *(float4*)(po + 4) = o1;
    }
}

// ---------------------------------------------------------------------------
extern "C" void kernel_launch(void* const* d_in, const int* in_sizes, int n_in,
                              void* d_out, int out_size, void* d_ws, size_t ws_size,
                              hipStream_t stream) {
    const int*   item   = (const int*)d_in[0];
    const int*   tix    = (const int*)d_in[1];
    const int*   frq    = (const int*)d_in[2];
    const float* Ei     = (const float*)d_in[3];
    const float* Et     = (const float*)d_in[4];
    const float* Ef     = (const float*)d_in[5];
    const float* W_xr   = (const float*)d_in[6];
    const float* W_hr   = (const float*)d_in[7];
    const float* b_r    = (const float*)d_in[8];
    const float* W_xz   = (const float*)d_in[9];
    const float* W_hz   = (const float*)d_in[10];
    const float* b_z    = (const float*)d_in[11];
    const float* W_xh   = (const float*)d_in[12];
    const float* W_hh   = (const float*)d_in[13];
    const float* b_h    = (const float*)d_in[14];
    const float* W_xtg  = (const float*)d_in[15];
    const float* W_tg   = (const float*)d_in[16];
    const float* b_tg   = (const float*)d_in[17];
    const float* W_xfg  = (const float*)d_in[18];
    const float* W_fg   = (const float*)d_in[19];
    const float* b_fg   = (const float*)d_in[20];
    const float* W_delta= (const float*)d_in[21];
    const float* b_delta= (const float*)d_in[22];
    const float* W_f_dir= (const float*)d_in[23];
    const float* b_f_dir= (const float*)d_in[24];
    const float* W_psi  = (const float*)d_in[25];
    const float* b_psi  = (const float*)d_in[26];
    // d_in[27] = W_a — dead (softmax over singleton axis == 1)
    const float* W_out  = (const float*)d_in[28];
    const float* b_out  = (const float*)d_in[29];
    float* out = (float*)d_out;

    float* ws   = (float*)d_ws;
    unsigned short* PRE  = (unsigned short*)(ws + PRE_OFF);    // bf16 PRE
    unsigned short* LOGb = (unsigned short*)(ws + LOG_OFF);    // bf16 logits
    unsigned short* WSWZ = (unsigned short*)(ws + WSWZ_OFF);
    unsigned short* WT   = (unsigned short*)(ws + WT_OFF);
    unsigned short* Hb   = (unsigned short*)(ws + HF_OFF);
    float* RSUM = ws + RSUM_OFF;

    k0_prep<<<12, 256, 0, stream>>>(
        W_xtg, W_tg, W_xfg, W_fg, W_xr, W_xz, W_xh,
        W_delta, W_delta + 128 * 128, W_f_dir, W_psi,
        W_psi /* pad slot 11, unused by k12 */,
        WSWZ, RSUM);
    k12_precompute<<<NTOK / 64, 256, 0, stream>>>(
        item, tix, frq, Ei, Et, Ef,
        b_r, b_z, b_h, b_tg, b_fg, b_delta, b_f_dir, b_psi,
        WSWZ, PRE);
    k3_scan<<<B_ + (NC + 127) / 128, 512, 0, stream>>>(
        PRE, W_hr, W_hz, W_hh, W_out, WT, Hb);
    k4a_logits<<<dim3((NC + 127) / 128, B_ / 64), 256, 0, stream>>>(
        Hb, WT, b_out, LOGb, RSUM);
    k4c_norm<<<dim3((NC / 8 + 255) / 256, B_), 256, 0, stream>>>(LOGb, RSUM, out);
}